// Round 6
// baseline (1553.218 us; speedup 1.0000x reference)
//
#include <hip/hip_runtime.h>
#include <hip/hip_bf16.h>
#include <cstdint>

// Problem constants
#define BB 64
#define SS 1024
#define DCn 64
#define Hn 128
#define G3 384

using f32x4 = __attribute__((ext_vector_type(4))) float;
using bf16x8 = __attribute__((ext_vector_type(8))) short;

__device__ __forceinline__ float sigmoid_f(float x) {
  return 1.0f / (1.0f + __expf(-x));
}
__device__ __forceinline__ float tanh_f(float x) {
  float xc = fminf(fmaxf(x, -15.0f), 15.0f);
  float t = __expf(-2.0f * xc);
  return (1.0f - t) / (1.0f + t);
}
__device__ __forceinline__ short f2bf(float x) {
  union { float f; uint32_t u; } v; v.f = x;
  uint32_t r = v.u + 0x7FFFu + ((v.u >> 16) & 1u);   // RNE
  return (short)(r >> 16);
}

// ---------------- Phase A: embeddings + conditional concat -> inter, concept
__global__ __launch_bounds__(256) void embed_kernel(
    const int* __restrict__ qseq, const int* __restrict__ cseq,
    const int* __restrict__ q2c, const int* __restrict__ q2cm,
    const float* __restrict__ cemb, const float* __restrict__ remb,
    float* __restrict__ inter, float* __restrict__ concept) {
  int pos = blockIdx.x * 2 + (threadIdx.x >> 7);   // [0, 65536)
  int d = threadIdx.x & 127;
  int q = qseq[pos];
  int corr = cseq[pos];
  float val;
  if (d < 64) {
    float acc = 0.f, msum = 0.f;
#pragma unroll
    for (int c = 0; c < 4; ++c) {
      int id = q2c[q * 4 + c];
      float m = (float)q2cm[q * 4 + c];
      acc += m * cemb[id * 64 + d];
      msum += m;
    }
    val = acc / fmaxf(msum, 1.0f);
    concept[(size_t)pos * 64 + d] = val;
  } else {
    val = remb[corr * 64 + (d - 64)];
  }
  // corr==1: [concept|corr]  else [corr|concept]
  int slot = (corr == 1) ? d : ((d < 64) ? d + 64 : d - 64);
  inter[(size_t)pos * 128 + slot] = val;
}

// ---------------- Generic f32 GEMM: C[M,N] = A[M,128] * Bm[N,128]^T + bias[N]
__global__ __launch_bounds__(256) void gemm_bt_kernel(
    const float* __restrict__ A, const float* __restrict__ Bm,
    const float* __restrict__ bias, float* __restrict__ C, int N) {
  __shared__ float4 As4[64][32];
  __shared__ float4 Bs4[64][32];
  const int m0 = blockIdx.x * 64;
  const int n0 = blockIdx.y * 64;
  const int tid = threadIdx.x;
  const float4* Ag = (const float4*)(A) + (size_t)m0 * 32;
  const float4* Bg = (const float4*)(Bm) + (size_t)n0 * 32;
#pragma unroll
  for (int l = 0; l < 8; ++l) {
    int idx = tid + l * 256;        // 0..2047
    int r = idx >> 5, k4 = idx & 31;
    int c = k4 ^ ((r >> 2) & 7);
    As4[r][c] = Ag[(size_t)r * 32 + k4];
    Bs4[r][c] = Bg[(size_t)r * 32 + k4];
  }
  __syncthreads();
  const int t16 = tid >> 4;  // 0..15 (row group)
  const int tn = tid & 15;   // 0..15 (col group)
  float acc[4][4] = {};
#pragma unroll
  for (int k4 = 0; k4 < 32; ++k4) {
    float4 a[4], b[4];
    int ca = k4 ^ (t16 & 7);
    int cb = k4 ^ (tn & 7);
#pragma unroll
    for (int i = 0; i < 4; ++i) a[i] = As4[t16 * 4 + i][ca];
#pragma unroll
    for (int j = 0; j < 4; ++j) b[j] = Bs4[tn * 4 + j][cb];
#pragma unroll
    for (int i = 0; i < 4; ++i)
#pragma unroll
      for (int j = 0; j < 4; ++j)
        acc[i][j] += a[i].x * b[j].x + a[i].y * b[j].y +
                     a[i].z * b[j].z + a[i].w * b[j].w;
  }
  float4 bv;
  bv.x = bias[n0 + tn * 4 + 0];
  bv.y = bias[n0 + tn * 4 + 1];
  bv.z = bias[n0 + tn * 4 + 2];
  bv.w = bias[n0 + tn * 4 + 3];
#pragma unroll
  for (int i = 0; i < 4; ++i) {
    float4 o;
    o.x = acc[i][0] + bv.x;
    o.y = acc[i][1] + bv.y;
    o.z = acc[i][2] + bv.z;
    o.w = acc[i][3] + bv.w;
    *(float4*)&C[(size_t)(m0 + t16 * 4 + i) * N + n0 + tn * 4] = o;
  }
}

// ---------------- Phase C: MFMA GRU. 4 blocks x 16 batches, 512 threads.
// Per step: gh[384,16] = W_hh[384,128] x h^T[128,16] via mfma_f32_16x16x32_bf16.
// Wave w owns gate-rows {w*16(r), 128+w*16(z), 256+w*16(n)}: r/z/n for the
// same (hdim,batch) land in the same lane&reg (C/D: col=lane&15=batch,
// row=(lane>>4)*4+reg=gate-dim). W_hh preconverted to bf16 A-frags in 48
// VGPRs (loaded once). h kept in LDS bf16 [16 batch][128 k], XOR-swizzled
// (byte ^= (batch&7)<<4): B-frag ds_read_b128 and h_new ds_write_b64 are
// both optimally bank-spread. A and B use the SAME k-mapping (k = (lane>>4)*8
// + j + 32*ksub), so any HW k-permutation cancels in the dot product.
__global__ __attribute__((amdgpu_flat_work_group_size(512, 512)))
__attribute__((amdgpu_waves_per_eu(2, 2))) void gru_kernel(
    const float* __restrict__ Xp, const float* __restrict__ W_hh,
    const float* __restrict__ b_hh, float* __restrict__ rnn_out) {
  const int tid = threadIdx.x;
  const int w = tid >> 6;          // wave 0..7 -> h-dims [w*16, w*16+16)
  const int lane = tid & 63;
  const int ln = lane & 15;        // batch within block / W row within tile
  const int c = lane >> 4;         // k-group 0..3
  const int b0 = blockIdx.x * 16;

  __shared__ short hlds[2048];     // 16 x 128 bf16 (4 KB), swizzled

  // --- preload W_hh bf16 A-fragments: wf[gate][ksub], row = base + ln,
  //     k = ksub*32 + c*8 + j  (same mapping as B-frag reads below)
  bf16x8 wf[3][4];
#pragma unroll
  for (int gt = 0; gt < 3; ++gt) {
    const float* wr = W_hh + (size_t)(gt * 128 + w * 16 + ln) * 128 + c * 8;
#pragma unroll
    for (int ks = 0; ks < 4; ++ks) {
      bf16x8 f;
#pragma unroll
      for (int j = 0; j < 8; ++j) f[j] = f2bf(wr[ks * 32 + j]);
      wf[gt][ks] = f;
    }
  }
  // --- per-reg biases (gate-dim rows w*16 + c*4 + reg)
  const f32x4 br = *(const f32x4*)(b_hh + w * 16 + c * 4);
  const f32x4 bz = *(const f32x4*)(b_hh + 128 + w * 16 + c * 4);
  const f32x4 bn = *(const f32x4*)(b_hh + 256 + w * 16 + c * 4);

  // zero h
  for (int i = tid; i < 1024; i += 512) ((uint32_t*)hlds)[i] = 0;

  const float* xb = Xp + (size_t)(b0 + ln) * SS * G3 + w * 16 + c * 4;
  float* rb = rnn_out + (size_t)(b0 + ln) * SS * Hn + w * 16 + c * 4;

  const int swz = (ln & 7) << 4;
  const char* hrd = (const char*)hlds + ln * 256;
  char* hwr = (char*)hlds + ln * 256 + ((w * 32 + c * 8) ^ swz);

  // depth-2 Xp prefetch
  f32x4 xrA = *(const f32x4*)(xb + 0);
  f32x4 xzA = *(const f32x4*)(xb + 128);
  f32x4 xnA = *(const f32x4*)(xb + 256);
  f32x4 xrB = *(const f32x4*)(xb + G3 + 0);
  f32x4 xzB = *(const f32x4*)(xb + G3 + 128);
  f32x4 xnB = *(const f32x4*)(xb + G3 + 256);

  f32x4 h_old = {0.f, 0.f, 0.f, 0.f};
  __syncthreads();

  for (int t = 0; t < SS; ++t) {
    // --- B-fragments of h^T from LDS (4 x ds_read_b128, swizzled)
    bf16x8 h0 = *(const bf16x8*)(hrd + ((0 * 64 + c * 16) ^ swz));
    bf16x8 h1 = *(const bf16x8*)(hrd + ((1 * 64 + c * 16) ^ swz));
    bf16x8 h2 = *(const bf16x8*)(hrd + ((2 * 64 + c * 16) ^ swz));
    bf16x8 h3 = *(const bf16x8*)(hrd + ((3 * 64 + c * 16) ^ swz));
    // --- prefetch Xp(t+2)
    f32x4 xrC = {0,0,0,0}, xzC = {0,0,0,0}, xnC = {0,0,0,0};
    if (t + 2 < SS) {
      const float* xp2 = xb + (size_t)(t + 2) * G3;
      xrC = *(const f32x4*)(xp2 + 0);
      xzC = *(const f32x4*)(xp2 + 128);
      xnC = *(const f32x4*)(xp2 + 256);
    }
    // keep W frags opaque/resident (loop-carried defs)
    asm volatile("" : "+v"(wf[0][0]), "+v"(wf[0][1]), "+v"(wf[0][2]), "+v"(wf[0][3]));
    asm volatile("" : "+v"(wf[1][0]), "+v"(wf[1][1]), "+v"(wf[1][2]), "+v"(wf[1][3]));
    asm volatile("" : "+v"(wf[2][0]), "+v"(wf[2][1]), "+v"(wf[2][2]), "+v"(wf[2][3]));
    // --- gh = W . h  (bias as C-in)
    f32x4 ar = br, az = bz, an = bn;
    ar = __builtin_amdgcn_mfma_f32_16x16x32_bf16(wf[0][0], h0, ar, 0, 0, 0);
    az = __builtin_amdgcn_mfma_f32_16x16x32_bf16(wf[1][0], h0, az, 0, 0, 0);
    an = __builtin_amdgcn_mfma_f32_16x16x32_bf16(wf[2][0], h0, an, 0, 0, 0);
    ar = __builtin_amdgcn_mfma_f32_16x16x32_bf16(wf[0][1], h1, ar, 0, 0, 0);
    az = __builtin_amdgcn_mfma_f32_16x16x32_bf16(wf[1][1], h1, az, 0, 0, 0);
    an = __builtin_amdgcn_mfma_f32_16x16x32_bf16(wf[2][1], h1, an, 0, 0, 0);
    ar = __builtin_amdgcn_mfma_f32_16x16x32_bf16(wf[0][2], h2, ar, 0, 0, 0);
    az = __builtin_amdgcn_mfma_f32_16x16x32_bf16(wf[1][2], h2, az, 0, 0, 0);
    an = __builtin_amdgcn_mfma_f32_16x16x32_bf16(wf[2][2], h2, an, 0, 0, 0);
    ar = __builtin_amdgcn_mfma_f32_16x16x32_bf16(wf[0][3], h3, ar, 0, 0, 0);
    az = __builtin_amdgcn_mfma_f32_16x16x32_bf16(wf[1][3], h3, az, 0, 0, 0);
    an = __builtin_amdgcn_mfma_f32_16x16x32_bf16(wf[2][3], h3, an, 0, 0, 0);
    __syncthreads();            // all B-frag reads done before h is overwritten
    // --- gates (elementwise, in C-layout registers)
    f32x4 hn_v;
#pragma unroll
    for (int q = 0; q < 4; ++q) {
      float r = sigmoid_f(xrA[q] + ar[q]);
      float z = sigmoid_f(xzA[q] + az[q]);
      float a = xnA[q] + r * an[q];
      float e = __expf(-2.0f * a);                       // tanh(a)=2/(1+e)-1
      float n = 2.0f * __builtin_amdgcn_rcpf(1.0f + e) - 1.0f;
      hn_v[q] = n + z * (h_old[q] - n);
    }
    h_old = hn_v;
    // --- h_new -> LDS (bf16, 4 consecutive k) + rnn_out (f32x4)
    union { short s[4]; uint2 u2; } pk;
#pragma unroll
    for (int q = 0; q < 4; ++q) pk.s[q] = f2bf(hn_v[q]);
    *(uint2*)hwr = pk.u2;
    *(f32x4*)(rb + (size_t)t * Hn) = hn_v;
    __syncthreads();            // h(t) fully written before t+1 reads
    xrA = xrB; xzA = xzB; xnA = xnB;
    xrB = xrC; xzB = xzC; xnB = xnC;
  }
}

// ---------------- Phase D2: s[pos] = sum_a tanh(tmpA[pos,a]) * sim_w[a]
__global__ __launch_bounds__(256) void score_kernel(
    const float* __restrict__ tmpA, const float* __restrict__ sim_w,
    float* __restrict__ s) {
  int pos = blockIdx.x * 4 + (threadIdx.x >> 6);
  int lane = threadIdx.x & 63;
  const float* row = tmpA + (size_t)pos * 128;
  float v = tanh_f(row[lane]) * sim_w[lane] +
            tanh_f(row[lane + 64]) * sim_w[lane + 64];
#pragma unroll
  for (int o = 32; o; o >>= 1) v += __shfl_down(v, o);
  if (lane == 0) s[pos] = v;
}

// ---------------- Phase E: cumulative softmax-average + exclusive cumsum -> excl
__global__ __launch_bounds__(128) void attn_kernel(
    const float* __restrict__ s, const float* __restrict__ rnn,
    float* __restrict__ excl) {
  const int b = blockIdx.x;
  const int h = threadIdx.x;      // 0..127
  __shared__ float elds[SS];
  __shared__ float red[2];
  const float* sb = s + (size_t)b * SS;
  float m = -1e30f;
  for (int i = h; i < SS; i += 128) m = fmaxf(m, sb[i]);
#pragma unroll
  for (int o = 32; o; o >>= 1) m = fmaxf(m, __shfl_down(m, o));
  if ((h & 63) == 0) red[h >> 6] = m;
  __syncthreads();
  m = fmaxf(red[0], red[1]);
  for (int i = h; i < SS; i += 128) elds[i] = __expf(sb[i] - m);
  __syncthreads();

  const float* rb = rnn + (size_t)b * SS * Hn;
  float* eb = excl + (size_t)b * SS * Hn;
  float num = 0.f, den = 0.f, run = 0.f;
  float rcur = rb[h];
  for (int t = 0; t < SS; ++t) {
    float rnxt = (t < SS - 1) ? rb[(size_t)(t + 1) * Hn + h] : 0.0f;
    float e = elds[t];
    den += e;
    num += e * rcur;
    eb[(size_t)t * Hn + h] = run;                    // exclusive
    run += num * __builtin_amdgcn_rcpf(den);         // attn_t
    rcur = rnxt;
  }
}

// ---------------- Phase F: logits -> sigmoid. One wave per (b, t).
__global__ __launch_bounds__(256) void out_kernel(
    const float* __restrict__ excl, const float* __restrict__ rnn,
    const float* __restrict__ concept, const float* __restrict__ pred_w,
    const float* __restrict__ pred_b, float* __restrict__ out) {
  int idx = blockIdx.x * 4 + (threadIdx.x >> 6);    // [0, 64*1023)
  int lane = threadIdx.x & 63;
  if (idx >= BB * (SS - 1)) return;
  int b = idx / (SS - 1), t = idx % (SS - 1);
  const float* e = excl + ((size_t)b * SS + t) * Hn;
  const float* r = rnn + ((size_t)b * SS + t) * Hn;
  const float* c = concept + ((size_t)b * SS + t + 1) * DCn;
  float v = e[lane] * pred_w[lane] + e[lane + 64] * pred_w[lane + 64] +
            r[lane] * pred_w[128 + lane] + r[lane + 64] * pred_w[192 + lane] +
            c[lane] * pred_w[256 + lane];
#pragma unroll
  for (int o = 32; o; o >>= 1) v += __shfl_down(v, o);
  if (lane == 0) out[idx] = sigmoid_f(v + pred_b[0]);
}

extern "C" void kernel_launch(void* const* d_in, const int* in_sizes, int n_in,
                              void* d_out, int out_size, void* d_ws, size_t ws_size,
                              hipStream_t stream) {
  const int* qseq = (const int*)d_in[0];
  const int* cseq = (const int*)d_in[1];
  const int* q2c = (const int*)d_in[2];
  const int* q2cm = (const int*)d_in[3];
  const float* cemb = (const float*)d_in[4];
  const float* remb = (const float*)d_in[5];
  const float* mlp_w = (const float*)d_in[6];
  const float* mlp_b = (const float*)d_in[7];
  const float* sim_w = (const float*)d_in[8];
  const float* W_ih = (const float*)d_in[9];
  const float* b_ih = (const float*)d_in[10];
  const float* W_hh = (const float*)d_in[11];
  const float* b_hh = (const float*)d_in[12];
  const float* pred_w = (const float*)d_in[13];
  const float* pred_b = (const float*)d_in[14];
  float* out = (float*)d_out;

  // workspace layout (f32 elements); total 46,137,344 floats = 176 MiB
  float* ws = (float*)d_ws;
  float* concept = ws;                 // 4,194,304  [B,S,64]   live A..F
  float* inter = ws + 4194304;         // 8,388,608  [B,S,128]  live A..B1
  float* Xp = ws + 12582912;           // 25,165,824 [B,S,384]  live B1..C
  float* rnn = ws + 37748736;          // 8,388,608  [B,S,128]  live C..F
  float* tmpA = inter;                 // alias (inter dead after B1)
  float* excl = Xp;                    // alias (Xp dead after C)
  float* sbuf = Xp + 8388608;          // alias, 256 KiB inside Xp region

  embed_kernel<<<32768, 256, 0, stream>>>(qseq, cseq, q2c, q2cm, cemb, remb,
                                          inter, concept);
  gemm_bt_kernel<<<dim3(1024, 6), 256, 0, stream>>>(inter, W_ih, b_ih, Xp, 384);
  gru_kernel<<<4, 512, 0, stream>>>(Xp, W_hh, b_hh, rnn);
  gemm_bt_kernel<<<dim3(1024, 2), 256, 0, stream>>>(rnn, mlp_w, mlp_b, tmpA, 128);
  score_kernel<<<16384, 256, 0, stream>>>(tmpA, sim_w, sbuf);
  attn_kernel<<<64, 128, 0, stream>>>(sbuf, rnn, excl);
  out_kernel<<<16368, 256, 0, stream>>>(excl, rnn, concept, pred_w, pred_b, out);
}

// Round 7
// 1436.329 us; speedup vs baseline: 1.0814x; 1.0814x over previous
//
#include <hip/hip_runtime.h>
#include <hip/hip_bf16.h>
#include <cstdint>

// Problem constants
#define BB 64
#define SS 1024
#define DCn 64
#define Hn 128
#define G3 384

using f32x4 = __attribute__((ext_vector_type(4))) float;
using bf16x8 = __attribute__((ext_vector_type(8))) short;

__device__ __forceinline__ float sigmoid_f(float x) {
  return 1.0f / (1.0f + __expf(-x));
}
__device__ __forceinline__ float tanh_f(float x) {
  float xc = fminf(fmaxf(x, -15.0f), 15.0f);
  float t = __expf(-2.0f * xc);
  return (1.0f - t) / (1.0f + t);
}
__device__ __forceinline__ short f2bf(float x) {
  union { float f; uint32_t u; } v; v.f = x;
  uint32_t r = v.u + 0x7FFFu + ((v.u >> 16) & 1u);   // RNE
  return (short)(r >> 16);
}
__device__ __forceinline__ f32x4 bf4f(ushort4 u) {
  union { uint32_t i; float f; } a, b, c, d;
  a.i = (uint32_t)u.x << 16; b.i = (uint32_t)u.y << 16;
  c.i = (uint32_t)u.z << 16; d.i = (uint32_t)u.w << 16;
  f32x4 r; r[0] = a.f; r[1] = b.f; r[2] = c.f; r[3] = d.f; return r;
}

// ---------------- Phase A: embeddings + conditional concat -> inter, concept
__global__ __launch_bounds__(256) void embed_kernel(
    const int* __restrict__ qseq, const int* __restrict__ cseq,
    const int* __restrict__ q2c, const int* __restrict__ q2cm,
    const float* __restrict__ cemb, const float* __restrict__ remb,
    float* __restrict__ inter, float* __restrict__ concept) {
  int pos = blockIdx.x * 2 + (threadIdx.x >> 7);   // [0, 65536)
  int d = threadIdx.x & 127;
  int q = qseq[pos];
  int corr = cseq[pos];
  float val;
  if (d < 64) {
    float acc = 0.f, msum = 0.f;
#pragma unroll
    for (int c = 0; c < 4; ++c) {
      int id = q2c[q * 4 + c];
      float m = (float)q2cm[q * 4 + c];
      acc += m * cemb[id * 64 + d];
      msum += m;
    }
    val = acc / fmaxf(msum, 1.0f);
    concept[(size_t)pos * 64 + d] = val;
  } else {
    val = remb[corr * 64 + (d - 64)];
  }
  // corr==1: [concept|corr]  else [corr|concept]
  int slot = (corr == 1) ? d : ((d < 64) ? d + 64 : d - 64);
  inter[(size_t)pos * 128 + slot] = val;
}

// ---------------- Generic f32 GEMM: C[M,N] = A[M,128] * Bm[N,128]^T + bias[N]
__global__ __launch_bounds__(256) void gemm_bt_kernel(
    const float* __restrict__ A, const float* __restrict__ Bm,
    const float* __restrict__ bias, float* __restrict__ C, int N) {
  __shared__ float4 As4[64][32];
  __shared__ float4 Bs4[64][32];
  const int m0 = blockIdx.x * 64;
  const int n0 = blockIdx.y * 64;
  const int tid = threadIdx.x;
  const float4* Ag = (const float4*)(A) + (size_t)m0 * 32;
  const float4* Bg = (const float4*)(Bm) + (size_t)n0 * 32;
#pragma unroll
  for (int l = 0; l < 8; ++l) {
    int idx = tid + l * 256;        // 0..2047
    int r = idx >> 5, k4 = idx & 31;
    int c = k4 ^ ((r >> 2) & 7);
    As4[r][c] = Ag[(size_t)r * 32 + k4];
    Bs4[r][c] = Bg[(size_t)r * 32 + k4];
  }
  __syncthreads();
  const int t16 = tid >> 4;  // 0..15 (row group)
  const int tn = tid & 15;   // 0..15 (col group)
  float acc[4][4] = {};
#pragma unroll
  for (int k4 = 0; k4 < 32; ++k4) {
    float4 a[4], b[4];
    int ca = k4 ^ (t16 & 7);
    int cb = k4 ^ (tn & 7);
#pragma unroll
    for (int i = 0; i < 4; ++i) a[i] = As4[t16 * 4 + i][ca];
#pragma unroll
    for (int j = 0; j < 4; ++j) b[j] = Bs4[tn * 4 + j][cb];
#pragma unroll
    for (int i = 0; i < 4; ++i)
#pragma unroll
      for (int j = 0; j < 4; ++j)
        acc[i][j] += a[i].x * b[j].x + a[i].y * b[j].y +
                     a[i].z * b[j].z + a[i].w * b[j].w;
  }
  float4 bv;
  bv.x = bias[n0 + tn * 4 + 0];
  bv.y = bias[n0 + tn * 4 + 1];
  bv.z = bias[n0 + tn * 4 + 2];
  bv.w = bias[n0 + tn * 4 + 3];
#pragma unroll
  for (int i = 0; i < 4; ++i) {
    float4 o;
    o.x = acc[i][0] + bv.x;
    o.y = acc[i][1] + bv.y;
    o.z = acc[i][2] + bv.z;
    o.w = acc[i][3] + bv.w;
    *(float4*)&C[(size_t)(m0 + t16 * 4 + i) * N + n0 + tn * 4] = o;
  }
}

// ---------------- Same GEMM but bf16 output (for Xp): halves write traffic
// and halves the GRU's streaming reads.
__global__ __launch_bounds__(256) void gemm_btb_kernel(
    const float* __restrict__ A, const float* __restrict__ Bm,
    const float* __restrict__ bias, ushort* __restrict__ C, int N) {
  __shared__ float4 As4[64][32];
  __shared__ float4 Bs4[64][32];
  const int m0 = blockIdx.x * 64;
  const int n0 = blockIdx.y * 64;
  const int tid = threadIdx.x;
  const float4* Ag = (const float4*)(A) + (size_t)m0 * 32;
  const float4* Bg = (const float4*)(Bm) + (size_t)n0 * 32;
#pragma unroll
  for (int l = 0; l < 8; ++l) {
    int idx = tid + l * 256;
    int r = idx >> 5, k4 = idx & 31;
    int c = k4 ^ ((r >> 2) & 7);
    As4[r][c] = Ag[(size_t)r * 32 + k4];
    Bs4[r][c] = Bg[(size_t)r * 32 + k4];
  }
  __syncthreads();
  const int t16 = tid >> 4;
  const int tn = tid & 15;
  float acc[4][4] = {};
#pragma unroll
  for (int k4 = 0; k4 < 32; ++k4) {
    float4 a[4], b[4];
    int ca = k4 ^ (t16 & 7);
    int cb = k4 ^ (tn & 7);
#pragma unroll
    for (int i = 0; i < 4; ++i) a[i] = As4[t16 * 4 + i][ca];
#pragma unroll
    for (int j = 0; j < 4; ++j) b[j] = Bs4[tn * 4 + j][cb];
#pragma unroll
    for (int i = 0; i < 4; ++i)
#pragma unroll
      for (int j = 0; j < 4; ++j)
        acc[i][j] += a[i].x * b[j].x + a[i].y * b[j].y +
                     a[i].z * b[j].z + a[i].w * b[j].w;
  }
  float4 bv;
  bv.x = bias[n0 + tn * 4 + 0];
  bv.y = bias[n0 + tn * 4 + 1];
  bv.z = bias[n0 + tn * 4 + 2];
  bv.w = bias[n0 + tn * 4 + 3];
#pragma unroll
  for (int i = 0; i < 4; ++i) {
    ushort4 o;
    o.x = (ushort)f2bf(acc[i][0] + bv.x);
    o.y = (ushort)f2bf(acc[i][1] + bv.y);
    o.z = (ushort)f2bf(acc[i][2] + bv.z);
    o.w = (ushort)f2bf(acc[i][3] + bv.w);
    *(ushort4*)&C[(size_t)(m0 + t16 * 4 + i) * N + n0 + tn * 4] = o;
  }
}

// ---------------- Phase C: MFMA GRU. 64 blocks x 1 batch, 512 threads.
// Per step: gh[384] = W_hh[384,128] x h[128] via mfma_f32_16x16x32_bf16 with
// all 16 B-cols carrying the SAME batch (wave-uniform addresses: LDS reads
// broadcast, Xp loads single-transaction). Wave w owns gate-rows
// {w*16(r), 128+w*16(z), 256+w*16(n)}; A and B use the SAME k-mapping
// (k = (lane>>4)*8 + j + 32*ks) so any HW k-permutation cancels.
// h double-buffered in LDS (bf16, 256B each): ONE barrier per step.
__global__ __attribute__((amdgpu_flat_work_group_size(512, 512)))
__attribute__((amdgpu_waves_per_eu(2, 2))) void gru_kernel(
    const ushort* __restrict__ Xp, const float* __restrict__ W_hh,
    const float* __restrict__ b_hh, float* __restrict__ rnn_out) {
  const int tid = threadIdx.x;
  const int w = tid >> 6;          // wave 0..7 -> h-dims [w*16, w*16+16)
  const int lane = tid & 63;
  const int ln = lane & 15;        // W row within tile (batch col duplicated)
  const int c = lane >> 4;         // k-group 0..3
  const int b = blockIdx.x;        // one batch per block

  __shared__ alignas(16) short hlds[2][128];   // bf16 h, double-buffered

  // --- preload W_hh bf16 A-fragments: wf[gate][ksub], row = base + ln,
  //     k = ks*32 + c*8 + j  (same mapping as B-frag reads below)
  bf16x8 wf[3][4];
#pragma unroll
  for (int gt = 0; gt < 3; ++gt) {
    const float* wr = W_hh + (size_t)(gt * 128 + w * 16 + ln) * 128 + c * 8;
#pragma unroll
    for (int ks = 0; ks < 4; ++ks) {
      bf16x8 f;
#pragma unroll
      for (int j = 0; j < 8; ++j) f[j] = f2bf(wr[ks * 32 + j]);
      wf[gt][ks] = f;
    }
  }
  // --- per-reg biases (gate-dim rows w*16 + c*4 + reg)
  const f32x4 br = *(const f32x4*)(b_hh + w * 16 + c * 4);
  const f32x4 bz = *(const f32x4*)(b_hh + 128 + w * 16 + c * 4);
  const f32x4 bn = *(const f32x4*)(b_hh + 256 + w * 16 + c * 4);

  if (tid < 128) hlds[0][tid] = 0;             // h(-1) = 0

  const ushort* xb = Xp + (size_t)b * SS * G3 + w * 16 + c * 4;
  float* rb = rnn_out + (size_t)b * SS * Hn + w * 16 + c * 4;

  // depth-2 Xp prefetch (wave-uniform addresses -> broadcast loads)
  ushort4 xrA = *(const ushort4*)(xb + 0);
  ushort4 xzA = *(const ushort4*)(xb + 128);
  ushort4 xnA = *(const ushort4*)(xb + 256);
  ushort4 xrB = *(const ushort4*)(xb + G3 + 0);
  ushort4 xzB = *(const ushort4*)(xb + G3 + 128);
  ushort4 xnB = *(const ushort4*)(xb + G3 + 256);

  f32x4 h_old = {0.f, 0.f, 0.f, 0.f};
  __syncthreads();

  for (int t = 0; t < SS; ++t) {
    // --- B-fragments of h from LDS buf[t&1] (broadcast, conflict-free)
    const short* hr = hlds[t & 1];
    bf16x8 h0 = *(const bf16x8*)(hr + 0 * 32 + c * 8);
    bf16x8 h1 = *(const bf16x8*)(hr + 1 * 32 + c * 8);
    bf16x8 h2 = *(const bf16x8*)(hr + 2 * 32 + c * 8);
    bf16x8 h3 = *(const bf16x8*)(hr + 3 * 32 + c * 8);
    // --- prefetch Xp(t+2)
    ushort4 xrC = {0, 0, 0, 0}, xzC = {0, 0, 0, 0}, xnC = {0, 0, 0, 0};
    if (t + 2 < SS) {
      const ushort* xp2 = xb + (size_t)(t + 2) * G3;
      xrC = *(const ushort4*)(xp2 + 0);
      xzC = *(const ushort4*)(xp2 + 128);
      xnC = *(const ushort4*)(xp2 + 256);
    }
    // keep W frags opaque/resident (loop-carried defs)
    asm volatile("" : "+v"(wf[0][0]), "+v"(wf[0][1]), "+v"(wf[0][2]), "+v"(wf[0][3]));
    asm volatile("" : "+v"(wf[1][0]), "+v"(wf[1][1]), "+v"(wf[1][2]), "+v"(wf[1][3]));
    asm volatile("" : "+v"(wf[2][0]), "+v"(wf[2][1]), "+v"(wf[2][2]), "+v"(wf[2][3]));
    // --- gh = W . h  (bias as C-in); 3 independent k-chains of 4
    f32x4 ar = br, az = bz, an = bn;
    ar = __builtin_amdgcn_mfma_f32_16x16x32_bf16(wf[0][0], h0, ar, 0, 0, 0);
    az = __builtin_amdgcn_mfma_f32_16x16x32_bf16(wf[1][0], h0, az, 0, 0, 0);
    an = __builtin_amdgcn_mfma_f32_16x16x32_bf16(wf[2][0], h0, an, 0, 0, 0);
    ar = __builtin_amdgcn_mfma_f32_16x16x32_bf16(wf[0][1], h1, ar, 0, 0, 0);
    az = __builtin_amdgcn_mfma_f32_16x16x32_bf16(wf[1][1], h1, az, 0, 0, 0);
    an = __builtin_amdgcn_mfma_f32_16x16x32_bf16(wf[2][1], h1, an, 0, 0, 0);
    ar = __builtin_amdgcn_mfma_f32_16x16x32_bf16(wf[0][2], h2, ar, 0, 0, 0);
    az = __builtin_amdgcn_mfma_f32_16x16x32_bf16(wf[1][2], h2, az, 0, 0, 0);
    an = __builtin_amdgcn_mfma_f32_16x16x32_bf16(wf[2][2], h2, an, 0, 0, 0);
    ar = __builtin_amdgcn_mfma_f32_16x16x32_bf16(wf[0][3], h3, ar, 0, 0, 0);
    az = __builtin_amdgcn_mfma_f32_16x16x32_bf16(wf[1][3], h3, az, 0, 0, 0);
    an = __builtin_amdgcn_mfma_f32_16x16x32_bf16(wf[2][3], h3, an, 0, 0, 0);
    // --- gates (all lanes compute duplicates; only ln==0 publishes)
    f32x4 xr = bf4f(xrA), xz = bf4f(xzA), xn = bf4f(xnA);
    f32x4 hn_v;
#pragma unroll
    for (int q = 0; q < 4; ++q) {
      float r = sigmoid_f(xr[q] + ar[q]);
      float z = sigmoid_f(xz[q] + az[q]);
      float a = xn[q] + r * an[q];
      float e = __expf(-2.0f * a);                       // tanh(a)=2/(1+e)-1
      float n = 2.0f * __builtin_amdgcn_rcpf(1.0f + e) - 1.0f;
      hn_v[q] = n + z * (h_old[q] - n);
    }
    h_old = hn_v;
    if (ln == 0) {
      union { short s[4]; uint2 u2; } pk;
#pragma unroll
      for (int q = 0; q < 4; ++q) pk.s[q] = f2bf(hn_v[q]);
      *(uint2*)(hlds[(t + 1) & 1] + w * 16 + c * 4) = pk.u2;   // h(t) -> other buf
      *(f32x4*)(rb + (size_t)t * Hn) = hn_v;                   // rnn_out
    }
    __syncthreads();             // h(t) visible before t+1 reads it
    xrA = xrB; xzA = xzB; xnA = xnB;
    xrB = xrC; xzB = xzC; xnB = xnC;
  }
}

// ---------------- Phase D2: s[pos] = sum_a tanh(tmpA[pos,a]) * sim_w[a]
__global__ __launch_bounds__(256) void score_kernel(
    const float* __restrict__ tmpA, const float* __restrict__ sim_w,
    float* __restrict__ s) {
  int pos = blockIdx.x * 4 + (threadIdx.x >> 6);
  int lane = threadIdx.x & 63;
  const float* row = tmpA + (size_t)pos * 128;
  float v = tanh_f(row[lane]) * sim_w[lane] +
            tanh_f(row[lane + 64]) * sim_w[lane + 64];
#pragma unroll
  for (int o = 32; o; o >>= 1) v += __shfl_down(v, o);
  if (lane == 0) s[pos] = v;
}

// ---------------- Phase E: cumulative softmax-average + exclusive cumsum.
// 128 blocks (b x h-half) x 64 threads: halves per-CU BW vs 64-block version.
__global__ __launch_bounds__(64) void attn_kernel(
    const float* __restrict__ s, const float* __restrict__ rnn,
    float* __restrict__ excl) {
  const int b = blockIdx.x >> 1;
  const int h = ((blockIdx.x & 1) << 6) + threadIdx.x;
  const int tl = threadIdx.x;     // 0..63
  __shared__ float elds[SS];
  const float* sb = s + (size_t)b * SS;
  float m = -1e30f;
  for (int i = tl; i < SS; i += 64) m = fmaxf(m, sb[i]);
#pragma unroll
  for (int o = 32; o; o >>= 1) m = fmaxf(m, __shfl_xor(m, o));
  for (int i = tl; i < SS; i += 64) elds[i] = __expf(sb[i] - m);
  __syncthreads();

  const float* rb = rnn + (size_t)b * SS * Hn + h;
  float* eb = excl + (size_t)b * SS * Hn + h;
  float num = 0.f, den = 0.f, run = 0.f;
  float rcur = rb[0];
  for (int t = 0; t < SS; ++t) {
    float rnxt = (t < SS - 1) ? rb[(size_t)(t + 1) * Hn] : 0.0f;
    float e = elds[t];
    den += e;
    num += e * rcur;
    eb[(size_t)t * Hn] = run;                        // exclusive
    run += num * __builtin_amdgcn_rcpf(den);         // attn_t
    rcur = rnxt;
  }
}

// ---------------- Phase F: logits -> sigmoid. One wave per (b, t).
__global__ __launch_bounds__(256) void out_kernel(
    const float* __restrict__ excl, const float* __restrict__ rnn,
    const float* __restrict__ concept, const float* __restrict__ pred_w,
    const float* __restrict__ pred_b, float* __restrict__ out) {
  int idx = blockIdx.x * 4 + (threadIdx.x >> 6);    // [0, 64*1023)
  int lane = threadIdx.x & 63;
  if (idx >= BB * (SS - 1)) return;
  int b = idx / (SS - 1), t = idx % (SS - 1);
  const float* e = excl + ((size_t)b * SS + t) * Hn;
  const float* r = rnn + ((size_t)b * SS + t) * Hn;
  const float* c = concept + ((size_t)b * SS + t + 1) * DCn;
  float v = e[lane] * pred_w[lane] + e[lane + 64] * pred_w[lane + 64] +
            r[lane] * pred_w[128 + lane] + r[lane + 64] * pred_w[192 + lane] +
            c[lane] * pred_w[256 + lane];
#pragma unroll
  for (int o = 32; o; o >>= 1) v += __shfl_down(v, o);
  if (lane == 0) out[idx] = sigmoid_f(v + pred_b[0]);
}

extern "C" void kernel_launch(void* const* d_in, const int* in_sizes, int n_in,
                              void* d_out, int out_size, void* d_ws, size_t ws_size,
                              hipStream_t stream) {
  const int* qseq = (const int*)d_in[0];
  const int* cseq = (const int*)d_in[1];
  const int* q2c = (const int*)d_in[2];
  const int* q2cm = (const int*)d_in[3];
  const float* cemb = (const float*)d_in[4];
  const float* remb = (const float*)d_in[5];
  const float* mlp_w = (const float*)d_in[6];
  const float* mlp_b = (const float*)d_in[7];
  const float* sim_w = (const float*)d_in[8];
  const float* W_ih = (const float*)d_in[9];
  const float* b_ih = (const float*)d_in[10];
  const float* W_hh = (const float*)d_in[11];
  const float* b_hh = (const float*)d_in[12];
  const float* pred_w = (const float*)d_in[13];
  const float* pred_b = (const float*)d_in[14];
  float* out = (float*)d_out;

  // workspace layout (f32 elements)
  float* ws = (float*)d_ws;
  float* concept = ws;                 // [B,S,64] f32,  live A..F
  float* inter = ws + 4194304;         // [B,S,128] f32, live A..B1
  ushort* Xp = (ushort*)(ws + 12582912); // [B,S,384] bf16 (50MB), live B1..C
  float* rnn = ws + 37748736;          // [B,S,128] f32, live C..F
  float* tmpA = inter;                 // alias (inter dead after B1)
  float* excl = ws + 12582912;         // alias over dead Xp region (33MB)
  float* sbuf = ws + 20971520;         // alias, after excl, inside dead Xp

  embed_kernel<<<32768, 256, 0, stream>>>(qseq, cseq, q2c, q2cm, cemb, remb,
                                          inter, concept);
  gemm_btb_kernel<<<dim3(1024, 6), 256, 0, stream>>>(inter, W_ih, b_ih, Xp, 384);
  gru_kernel<<<64, 512, 0, stream>>>(Xp, W_hh, b_hh, rnn);
  gemm_bt_kernel<<<dim3(1024, 2), 256, 0, stream>>>(rnn, mlp_w, mlp_b, tmpA, 128);
  score_kernel<<<16384, 256, 0, stream>>>(tmpA, sim_w, sbuf);
  attn_kernel<<<128, 64, 0, stream>>>(sbuf, rnn, excl);
  out_kernel<<<16368, 256, 0, stream>>>(excl, rnn, concept, pred_w, pred_b, out);
}